// Round 7
// baseline (410.164 us; speedup 1.0000x reference)
//
#include <hip/hip_runtime.h>
#include <hip/hip_bf16.h>

#define N_PTS 8192
#define KNN 8

typedef __attribute__((ext_vector_type(8))) short short8;
typedef __attribute__((ext_vector_type(4))) float float4v;
typedef unsigned long long u64;

// f32 -> bf16 round-to-nearest-even (finite inputs only)
static __device__ __forceinline__ short f2bf(float f) {
    unsigned u = __float_as_uint(f);
    unsigned r = (u + 0x7FFFu + ((u >> 16) & 1u)) >> 16;
    return (short)r;
}
static __device__ __forceinline__ float bf2f(short s) {
    return __uint_as_float(((unsigned)(unsigned short)s) << 16);
}

// ---------------------------------------------------------------------------
// KNN stage 1 v4: 512 blocks x 256 threads; block = (query-group of 256) x
// (candidate partition of 1024). One query per thread. Candidates staged in
// LDS as float4 (x,y,z,|c|^2/2); all inner reads are wave-uniform broadcasts.
// Phase 1 key: monotone score s = |c|^2/2 - c.q  (3 fma + min = 4 VALU/cand).
// Threshold t = 8th smallest of 32 rotating bucket minima (valid upper bound:
// 8 distinct elements have s <= t) + 1e-4 margin covering worst-case f32
// score error, so every exact-top-8 element is provably collected. Hits are
// RE-SCORED with exact-difference d2 before the final u64 (d2bits<<32|idx)
// top-8 -- selected sets bit-identical to the verified rounds 1-5.
// Overflow (>16 hits) -> exact rescan fallback.
// ---------------------------------------------------------------------------
__global__ __launch_bounds__(256) void knn_partial(const float* __restrict__ pos,
                                                   u64* __restrict__ partial)
{
    __shared__ float4 sc[1024];        // (x,y,z,sw) 16 KB
    __shared__ u64 buf[256][17];       // 16 slots + trash, 34.8 KB

    const int tid = threadIdx.x;
    const int p   = blockIdx.x & 7;          // partition 0..7
    const int qg  = blockIdx.x >> 3;         // query group 0..63
    const int batch = qg >> 5;
    const int q_in_b = (qg & 31) * 256 + tid;
    const float* bpos = pos + (long)batch * N_PTS * 3;

    // stage 1024 candidates: 4 points (3 float4) per thread, compute sw
    {
        const float* src = bpos + (p * 1024 + tid * 4) * 3;
        const float4 f0 = *(const float4*)(src);
        const float4 f1 = *(const float4*)(src + 4);
        const float4 f2 = *(const float4*)(src + 8);
        sc[tid * 4 + 0] = make_float4(f0.x, f0.y, f0.z,
            0.5f * fmaf(f0.x, f0.x, fmaf(f0.y, f0.y, f0.z * f0.z)));
        sc[tid * 4 + 1] = make_float4(f0.w, f1.x, f1.y,
            0.5f * fmaf(f0.w, f0.w, fmaf(f1.x, f1.x, f1.y * f1.y)));
        sc[tid * 4 + 2] = make_float4(f1.z, f1.w, f2.x,
            0.5f * fmaf(f1.z, f1.z, fmaf(f1.w, f1.w, f2.x * f2.x)));
        sc[tid * 4 + 3] = make_float4(f2.y, f2.z, f2.w,
            0.5f * fmaf(f2.y, f2.y, fmaf(f2.z, f2.z, f2.w * f2.w)));
    }
    __syncthreads();

    const float qx = bpos[q_in_b * 3 + 0];
    const float qy = bpos[q_in_b * 3 + 1];
    const float qz = bpos[q_in_b * 3 + 2];

    // ---- phase 1: branchless 32 rotating bucket minima (score space) -----
    float bmin[32];
#pragma unroll
    for (int j = 0; j < 32; ++j) bmin[j] = 3.0e38f;

    for (int base = 0; base < 1024; base += 32) {
#pragma unroll
        for (int j = 0; j < 32; ++j) {
            const float4 c = sc[base + j];
            const float s = fmaf(-qx, c.x, fmaf(-qy, c.y, fmaf(-qz, c.z, c.w)));
            bmin[j] = fminf(bmin[j], s);
        }
    }

    // ---- threshold: 8th smallest of 32 bucket minima + safety margin -----
    float t8[8];
#pragma unroll
    for (int j = 0; j < 8; ++j) t8[j] = 3.0e38f;
#pragma unroll
    for (int i = 0; i < 32; ++i) {
        float x = bmin[i];
#pragma unroll
        for (int j = 0; j < 8; ++j) {
            const float lo = fminf(t8[j], x);
            const float hi = fmaxf(t8[j], x);
            t8[j] = lo; x = hi;
        }
    }
    const float t = t8[7] + 1e-4f;

    // ---- phase 2: collect s <= t; exact-diff d2 on hit -------------------
    int cnt = 0;
    for (int i = 0; i < 1024; ++i) {
        const float4 c = sc[i];
        const float s = fmaf(-qx, c.x, fmaf(-qy, c.y, fmaf(-qz, c.z, c.w)));
        if (s <= t) {
            const float dx = c.x - qx, dy = c.y - qy, dz = c.z - qz;
            const float d2 = fmaf(dx, dx, fmaf(dy, dy, dz * dz));
            buf[tid][cnt < 16 ? cnt : 16] =
                ((u64)__float_as_uint(d2) << 32) | (unsigned)(p * 1024 + i);
            ++cnt;
        }
    }

    // ---- exact top-8 over collected (or rare exact fallback) -------------
    u64 best[8];
#pragma unroll
    for (int j = 0; j < 8; ++j) best[j] = ~0ULL;

    if (cnt <= 16) {
        for (int u = 0; u < cnt; ++u) {
            u64 x = buf[tid][u];
#pragma unroll
            for (int j = 0; j < 8; ++j) {
                const u64 lo = x < best[j] ? x : best[j];
                const u64 hi = x < best[j] ? best[j] : x;
                best[j] = lo; x = hi;
            }
        }
    } else {
        for (int i = 0; i < 1024; ++i) {    // statistically-never fallback
            const float4 c = sc[i];
            const float dx = c.x - qx, dy = c.y - qy, dz = c.z - qz;
            const float d2 = fmaf(dx, dx, fmaf(dy, dy, dz * dz));
            u64 x = ((u64)__float_as_uint(d2) << 32) | (unsigned)(p * 1024 + i);
            if (x < best[7]) {
#pragma unroll
                for (int j = 0; j < 8; ++j) {
                    const u64 lo = x < best[j] ? x : best[j];
                    const u64 hi = x < best[j] ? best[j] : x;
                    best[j] = lo; x = hi;
                }
            }
        }
    }

    const long qglob = (long)batch * N_PTS + q_in_b;
#pragma unroll
    for (int j = 0; j < 8; ++j)
        partial[(long)(p * 8 + j) * 16384 + qglob] = best[j];   // coalesced
}

// ---------------------------------------------------------------------------
// KNN stage 2: merge 8 partitions x 8 slots per query (slot-major, coalesced).
// ---------------------------------------------------------------------------
__global__ __launch_bounds__(256) void knn_merge(const u64* __restrict__ partial,
                                                 int* __restrict__ idxo)
{
    const int q = blockIdx.x * 256 + threadIdx.x;
    u64 best[8];
#pragma unroll
    for (int j = 0; j < 8; ++j) best[j] = ~0ULL;
    for (int s = 0; s < 64; ++s) {
        u64 x = partial[(long)s * 16384 + q];
        if (x < best[7]) {
#pragma unroll
            for (int j = 0; j < 8; ++j) {
                const u64 lo = x < best[j] ? x : best[j];
                const u64 hi = x < best[j] ? best[j] : x;
                best[j] = lo; x = hi;
            }
        }
    }
#pragma unroll
    for (int j = 0; j < 8; ++j)
        idxo[(long)q * 8 + j] = (int)(best[j] & 0xFFFFFFFFu);
}

// ---------------------------------------------------------------------------
// f32 -> bf16 bulk convert (8 elements/thread).
// ---------------------------------------------------------------------------
__global__ __launch_bounds__(256) void conv_x(const float* __restrict__ x,
                                              short* __restrict__ xb)
{
    const int i = blockIdx.x * 256 + threadIdx.x;
    const float4 a = ((const float4*)x)[i * 2];
    const float4 b = ((const float4*)x)[i * 2 + 1];
    short8 w = {f2bf(a.x), f2bf(a.y), f2bf(a.z), f2bf(a.w),
                f2bf(b.x), f2bf(b.y), f2bf(b.z), f2bf(b.w)};
    ((short8*)xb)[i] = w;
}

// W[K][N] f32 -> Wt[N][K] bf16. kshift = log2(K). Tiny matrices, L2-resident.
__global__ __launch_bounds__(256) void conv_wt(const float* __restrict__ W,
                                               short* __restrict__ Wt,
                                               int kshift, int N)
{
    const int o = blockIdx.x * 256 + threadIdx.x;   // output index n*K+k
    const int K = 1 << kshift;
    const int n = o >> kshift;
    const int k = o & (K - 1);
    Wt[o] = f2bf(W[(long)k * N + n]);
}

// ---------------------------------------------------------------------------
// bf16 MFMA GEMM, both operands pre-converted: C[M,N] = A[M,K] * Bt[N,K]^T.
// 128x128 tile, BK=32, 4 waves 2x2 of 64x64, 16x16x32 MFMA (layouts per
// m89/m91, identical to rounds 4-5 which passed). LDS rows padded to 40
// shorts (80B). Staging: 2 threads/row, EACH THREAD WRITES 16 SHORTS
// (two short8s) -- 256 thr x 16 = 4096 = 128 rows x 32 k. (Round-6 bug:
// only one short8/thread left half the tile uninitialized -> NaN.)
// OUTBF16: C bf16; else f32 + optional bias.
// ---------------------------------------------------------------------------
template<int OUTBF16>
__global__ __launch_bounds__(256) void gemm_tt(const short* __restrict__ A,
                                               const short* __restrict__ Bt,
                                               const float* __restrict__ bias,
                                               void* __restrict__ C_,
                                               int N, int Kd)
{
    __shared__ short As[128][40];
    __shared__ short Bs[128][40];

    const int tid  = threadIdx.x;
    const int lane = tid & 63;
    const int wv   = tid >> 6;
    const int quad = lane >> 4;
    const int l15  = lane & 15;
    const int m0 = blockIdx.y * 128;
    const int n0 = blockIdx.x * 128;
    const int mh = (wv & 1) * 64, nh = (wv >> 1) * 64;

    const int srow  = tid >> 1;          // 0..127
    const int shalf = (tid & 1) * 16;    // 0 or 16

    float4v acc[4][4];
#pragma unroll
    for (int i = 0; i < 4; ++i)
#pragma unroll
        for (int j = 0; j < 4; ++j) acc[i][j] = (float4v)(0.f);

    for (int k0 = 0; k0 < Kd; k0 += 32) {
        const short8* asrc = (const short8*)(A + (long)(m0 + srow) * Kd + k0 + shalf);
        const short8* bsrc = (const short8*)(Bt + (long)(n0 + srow) * Kd + k0 + shalf);
        *(short8*)&As[srow][shalf]     = asrc[0];
        *(short8*)&As[srow][shalf + 8] = asrc[1];
        *(short8*)&Bs[srow][shalf]     = bsrc[0];
        *(short8*)&Bs[srow][shalf + 8] = bsrc[1];
        __syncthreads();

        short8 af[4], bfv[4];
#pragma unroll
        for (int i = 0; i < 4; ++i)
            af[i] = *(const short8*)&As[mh + i * 16 + l15][quad * 8];
#pragma unroll
        for (int j = 0; j < 4; ++j)
            bfv[j] = *(const short8*)&Bs[nh + j * 16 + l15][quad * 8];
#pragma unroll
        for (int i = 0; i < 4; ++i)
#pragma unroll
            for (int j = 0; j < 4; ++j)
                acc[i][j] = __builtin_amdgcn_mfma_f32_16x16x32_bf16(af[i], bfv[j], acc[i][j], 0, 0, 0);
        __syncthreads();
    }

#pragma unroll
    for (int i = 0; i < 4; ++i)
#pragma unroll
        for (int j = 0; j < 4; ++j) {
            const int col = n0 + nh + j * 16 + l15;
            const float bb = (!OUTBF16 && bias) ? bias[col] : 0.f;
#pragma unroll
            for (int r = 0; r < 4; ++r) {
                const int row = m0 + mh + i * 16 + quad * 4 + r;
                if (OUTBF16) {
                    ((short*)C_)[(long)row * N + col] = f2bf(acc[i][j][r]);
                } else {
                    ((float*)C_)[(long)row * N + col] = acc[i][j][r] + bb;
                }
            }
        }
}

// ---------------------------------------------------------------------------
// Fused KNN attention, bf16 storage / f32 math (unchanged from round 5).
// ---------------------------------------------------------------------------
__global__ __launch_bounds__(256) void attn_kernel(const short* qall,
                                                   const short* __restrict__ kvall,
                                                   const int* __restrict__ idxp,
                                                   short* outp)
{
    __shared__ float attn_s[4][8][8];
    const int wave = threadIdx.x >> 6;
    const int lane = threadIdx.x & 63;
    const int g = blockIdx.x * 4 + wave;
    const int b = g >> 13;
    const int* myidx = idxp + (long)g * 8;

    {
        const int h = lane >> 3;
        const int k = lane & 7;
        const int j = myidx[k];
        const short8* qrow = (const short8*)(qall + (long)g * 512 + h * 64);
        const short8* krow = (const short8*)(kvall + ((long)(b * N_PTS + j)) * 1024 + h * 64);

        float dot = 0.f;
#pragma unroll
        for (int c = 0; c < 8; ++c) {
            const short8 qv = qrow[c];
            const short8 kv = krow[c];
#pragma unroll
            for (int e = 0; e < 8; ++e)
                dot = fmaf(bf2f(qv[e]), bf2f(kv[e]), dot);
        }
        dot *= 0.125f;

        float m = dot;
#pragma unroll
        for (int off = 1; off < 8; off <<= 1)
            m = fmaxf(m, __shfl_xor(m, off, 8));
        const float e = __expf(dot - m);
        float ssum = e;
#pragma unroll
        for (int off = 1; off < 8; off <<= 1)
            ssum += __shfl_xor(ssum, off, 8);
        attn_s[wave][h][k] = e / ssum;
    }
    __syncthreads();                      // drains q reads before aliased writes

    const int d8 = lane * 8;
    const int h2 = lane >> 3;
    float o[8] = {0.f, 0.f, 0.f, 0.f, 0.f, 0.f, 0.f, 0.f};
#pragma unroll
    for (int kk = 0; kk < 8; ++kk) {
        const int jj = myidx[kk];
        const float w = attn_s[wave][h2][kk];
        const short8 v = *(const short8*)(kvall + ((long)(b * N_PTS + jj)) * 1024 + 512 + d8);
#pragma unroll
        for (int e = 0; e < 8; ++e)
            o[e] = fmaf(w, bf2f(v[e]), o[e]);
    }
    short8 ov = {f2bf(o[0]), f2bf(o[1]), f2bf(o[2]), f2bf(o[3]),
                 f2bf(o[4]), f2bf(o[5]), f2bf(o[6]), f2bf(o[7])};
    *(short8*)(outp + (long)g * 512 + d8) = ov;
}

// ---------------------------------------------------------------------------
extern "C" void kernel_launch(void* const* d_in, const int* in_sizes, int n_in,
                              void* d_out, int out_size, void* d_ws, size_t ws_size,
                              hipStream_t stream)
{
    const float* x    = (const float*)d_in[0];  // [2,8192,256]
    const float* pos  = (const float*)d_in[1];  // [2,8192,3]
    const float* Wq   = (const float*)d_in[2];  // [256,512]
    const float* Wkv  = (const float*)d_in[3];  // [256,1024]
    const float* Wout = (const float*)d_in[4];  // [512,256]
    const float* bout = (const float*)d_in[5];  // [256]
    float* out = (float*)d_out;                 // [2,8192,256] f32

    const int M = 16384;

    // workspace layout:
    char* ws = (char*)d_ws;
    int*   idxp  = (int*)ws;                          ws += 1 << 19;  // 512 KB
    short* qall  = (short*)ws;                        ws += (long)M * 512 * 2;   // 16 MB
    short* kvall = (short*)ws;                        ws += (long)M * 1024 * 2;  // 32 MB
    short* xb    = (short*)ws;                        ws += (long)M * 256 * 2;   // 8 MB
    short* wqt   = (short*)ws;                        ws += 512 * 256 * 2;
    short* wkvt  = (short*)ws;                        ws += 1024 * 256 * 2;
    short* woutt = (short*)ws;                        ws += 256 * 512 * 2;
    // knn scratch (8.4 MB) aliases kvall; consumed by merge before kv-gemm
    u64* partial = (u64*)kvall;

    knn_partial<<<512, 256, 0, stream>>>(pos, partial);
    knn_merge<<<64, 256, 0, stream>>>(partial, idxp);

    conv_x<<<2048, 256, 0, stream>>>(x, xb);
    conv_wt<<<512, 256, 0, stream>>>(Wq, wqt, 8, 512);       // [256,512] -> [512,256]
    conv_wt<<<1024, 256, 0, stream>>>(Wkv, wkvt, 8, 1024);   // [256,1024] -> [1024,256]
    conv_wt<<<512, 256, 0, stream>>>(Wout, woutt, 9, 256);   // [512,256] -> [256,512]

    gemm_tt<1><<<dim3(4, 128), 256, 0, stream>>>(xb, wqt, nullptr, qall, 512, 256);
    gemm_tt<1><<<dim3(8, 128), 256, 0, stream>>>(xb, wkvt, nullptr, kvall, 1024, 256);
    attn_kernel<<<M / 4, 256, 0, stream>>>(qall, kvall, idxp, qall);   // in-place
    gemm_tt<0><<<dim3(2, 128), 256, 0, stream>>>(qall, woutt, bout, out, 256, 512);
}

// Round 8
// 342.334 us; speedup vs baseline: 1.1981x; 1.1981x over previous
//
#include <hip/hip_runtime.h>
#include <hip/hip_bf16.h>

#define N_PTS 8192
#define KNN 8

typedef __attribute__((ext_vector_type(8))) short short8;
typedef __attribute__((ext_vector_type(4))) float float4v;
typedef unsigned long long u64;

// f32 -> bf16 round-to-nearest-even (finite inputs only)
static __device__ __forceinline__ short f2bf(float f) {
    unsigned u = __float_as_uint(f);
    unsigned r = (u + 0x7FFFu + ((u >> 16) & 1u)) >> 16;
    return (short)r;
}
static __device__ __forceinline__ float bf2f(short s) {
    return __uint_as_float(((unsigned)(unsigned short)s) << 16);
}

// ---------------------------------------------------------------------------
// KNN stage 1 v5 = round-5 structure (1024 blocks x 256 thr, 16 partitions of
// 512, SoA LDS, 3-4 blocks/CU) + round-7 score algebra (4 VALU/candidate).
// One query per thread. LDS: sx/sy/sz/sw where sw=|c|^2/2; all inner reads
// wave-uniform float4 broadcasts. Phase 1 key: monotone score s = sw - c.q
// (3 fma + min). Threshold t = 8th smallest of 32 rotating bucket minima
// (the 8 buckets with smallest minima contain 8 distinct elements <= t, so
// s(8) <= t) + 1e-4 margin >> worst-case f32 score error -> every true
// top-8 element is provably collected. Hits are RE-SCORED with the exact-
// difference d2, so final selected sets are bit-identical to the verified
// exact-selection rounds 1-5. Overflow (>16 hits) -> exact rescan fallback.
// ---------------------------------------------------------------------------
__global__ __launch_bounds__(256) void knn_partial(const float* __restrict__ pos,
                                                   u64* __restrict__ partial)
{
    __shared__ float sx[512], sy[512], sz[512], sw[512];  // 8 KB SoA
    __shared__ u64 buf[256][17];                          // 34.8 KB collect

    const int tid = threadIdx.x;
    const int p   = blockIdx.x & 15;           // candidate partition 0..15
    const int qg  = blockIdx.x >> 4;           // query group 0..63
    const int batch = qg >> 5;
    const int q_in_b = (qg & 31) * 256 + tid;
    const float* bpos = pos + (long)batch * N_PTS * 3;

    // stage partition p (512 candidates, AoS float3 -> SoA + |c|^2/2)
    if (tid < 128) {
        const float* src = bpos + (p * 512 + tid * 4) * 3;
        const float4 f0 = *(const float4*)(src);
        const float4 f1 = *(const float4*)(src + 4);
        const float4 f2 = *(const float4*)(src + 8);
        const int c0 = tid * 4;
        const float4 X = make_float4(f0.x, f0.w, f1.z, f2.y);
        const float4 Y = make_float4(f0.y, f1.x, f1.w, f2.z);
        const float4 Z = make_float4(f0.z, f1.y, f2.x, f2.w);
        *(float4*)&sx[c0] = X;
        *(float4*)&sy[c0] = Y;
        *(float4*)&sz[c0] = Z;
        *(float4*)&sw[c0] = make_float4(
            0.5f * fmaf(X.x, X.x, fmaf(Y.x, Y.x, Z.x * Z.x)),
            0.5f * fmaf(X.y, X.y, fmaf(Y.y, Y.y, Z.y * Z.y)),
            0.5f * fmaf(X.z, X.z, fmaf(Y.z, Y.z, Z.z * Z.z)),
            0.5f * fmaf(X.w, X.w, fmaf(Y.w, Y.w, Z.w * Z.w)));
    }
    __syncthreads();

    const float qx = bpos[q_in_b * 3 + 0];
    const float qy = bpos[q_in_b * 3 + 1];
    const float qz = bpos[q_in_b * 3 + 2];

    const float4* vx = (const float4*)sx;
    const float4* vy = (const float4*)sy;
    const float4* vz = (const float4*)sz;
    const float4* vw = (const float4*)sw;

    // ---- phase 1: branchless 32 rotating bucket minima (score space) -----
    float bmin[32];
#pragma unroll
    for (int j = 0; j < 32; ++j) bmin[j] = 3.0e38f;

    for (int base = 0; base < 128; base += 8) {
#pragma unroll
        for (int g = 0; g < 8; ++g) {
            const float4 cx = vx[base + g];
            const float4 cy = vy[base + g];
            const float4 cz = vz[base + g];
            const float4 cw = vw[base + g];
            bmin[g*4+0] = fminf(bmin[g*4+0], fmaf(-qx, cx.x, fmaf(-qy, cy.x, fmaf(-qz, cz.x, cw.x))));
            bmin[g*4+1] = fminf(bmin[g*4+1], fmaf(-qx, cx.y, fmaf(-qy, cy.y, fmaf(-qz, cz.y, cw.y))));
            bmin[g*4+2] = fminf(bmin[g*4+2], fmaf(-qx, cx.z, fmaf(-qy, cy.z, fmaf(-qz, cz.z, cw.z))));
            bmin[g*4+3] = fminf(bmin[g*4+3], fmaf(-qx, cx.w, fmaf(-qy, cy.w, fmaf(-qz, cz.w, cw.w))));
        }
    }

    // ---- threshold: 8th smallest of 32 bucket minima + safety margin -----
    float t8[8];
#pragma unroll
    for (int j = 0; j < 8; ++j) t8[j] = 3.0e38f;
#pragma unroll
    for (int i = 0; i < 32; ++i) {
        float x = bmin[i];
#pragma unroll
        for (int j = 0; j < 8; ++j) {
            const float lo = fminf(t8[j], x);
            const float hi = fmaxf(t8[j], x);
            t8[j] = lo; x = hi;
        }
    }
    const float t = t8[7] + 1e-4f;

    // ---- phase 2: collect s <= t; exact-diff d2 on hit -------------------
    int cnt = 0;
    for (int base = 0; base < 128; ++base) {
        const float4 cx = vx[base];
        const float4 cy = vy[base];
        const float4 cz = vz[base];
        const float4 cw = vw[base];
#pragma unroll
        for (int j = 0; j < 4; ++j) {
            const float ccx = j == 0 ? cx.x : j == 1 ? cx.y : j == 2 ? cx.z : cx.w;
            const float ccy = j == 0 ? cy.x : j == 1 ? cy.y : j == 2 ? cy.z : cy.w;
            const float ccz = j == 0 ? cz.x : j == 1 ? cz.y : j == 2 ? cz.z : cz.w;
            const float ccw = j == 0 ? cw.x : j == 1 ? cw.y : j == 2 ? cw.z : cw.w;
            const float s = fmaf(-qx, ccx, fmaf(-qy, ccy, fmaf(-qz, ccz, ccw)));
            if (s <= t) {
                const float dx = ccx - qx, dy = ccy - qy, dz = ccz - qz;
                const float d2 = fmaf(dx, dx, fmaf(dy, dy, dz * dz));
                buf[tid][cnt < 16 ? cnt : 16] =
                    ((u64)__float_as_uint(d2) << 32)
                    | (unsigned)(p * 512 + base * 4 + j);
                ++cnt;
            }
        }
    }

    // ---- exact top-8 over collected (or rare exact fallback) -------------
    u64 best[8];
#pragma unroll
    for (int j = 0; j < 8; ++j) best[j] = ~0ULL;

    if (cnt <= 16) {
        for (int u = 0; u < cnt; ++u) {
            u64 x = buf[tid][u];
#pragma unroll
            for (int j = 0; j < 8; ++j) {
                const u64 lo = x < best[j] ? x : best[j];
                const u64 hi = x < best[j] ? best[j] : x;
                best[j] = lo; x = hi;
            }
        }
    } else {
        for (int i = 0; i < 512; ++i) {     // statistically-never fallback
            const float dx = sx[i] - qx, dy = sy[i] - qy, dz = sz[i] - qz;
            const float d2 = fmaf(dx, dx, fmaf(dy, dy, dz * dz));
            u64 x = ((u64)__float_as_uint(d2) << 32) | (unsigned)(p * 512 + i);
            if (x < best[7]) {
#pragma unroll
                for (int j = 0; j < 8; ++j) {
                    const u64 lo = x < best[j] ? x : best[j];
                    const u64 hi = x < best[j] ? best[j] : x;
                    best[j] = lo; x = hi;
                }
            }
        }
    }

    const long qglob = (long)batch * N_PTS + q_in_b;
#pragma unroll
    for (int j = 0; j < 8; ++j)
        partial[(long)(p * 8 + j) * 16384 + qglob] = best[j];   // coalesced
}

// ---------------------------------------------------------------------------
// KNN stage 2: merge 16 partitions x 8 slots per query (slot-major, coalesced).
// ---------------------------------------------------------------------------
__global__ __launch_bounds__(256) void knn_merge(const u64* __restrict__ partial,
                                                 int* __restrict__ idxo)
{
    const int q = blockIdx.x * 256 + threadIdx.x;
    u64 best[8];
#pragma unroll
    for (int j = 0; j < 8; ++j) best[j] = ~0ULL;
    for (int s = 0; s < 128; ++s) {
        u64 x = partial[(long)s * 16384 + q];
        if (x < best[7]) {
#pragma unroll
            for (int j = 0; j < 8; ++j) {
                const u64 lo = x < best[j] ? x : best[j];
                const u64 hi = x < best[j] ? best[j] : x;
                best[j] = lo; x = hi;
            }
        }
    }
#pragma unroll
    for (int j = 0; j < 8; ++j)
        idxo[(long)q * 8 + j] = (int)(best[j] & 0xFFFFFFFFu);
}

// ---------------------------------------------------------------------------
// f32 -> bf16 bulk convert (8 elements/thread).
// ---------------------------------------------------------------------------
__global__ __launch_bounds__(256) void conv_x(const float* __restrict__ x,
                                              short* __restrict__ xb)
{
    const int i = blockIdx.x * 256 + threadIdx.x;
    const float4 a = ((const float4*)x)[i * 2];
    const float4 b = ((const float4*)x)[i * 2 + 1];
    short8 w = {f2bf(a.x), f2bf(a.y), f2bf(a.z), f2bf(a.w),
                f2bf(b.x), f2bf(b.y), f2bf(b.z), f2bf(b.w)};
    ((short8*)xb)[i] = w;
}

// W[K][N] f32 -> Wt[N][K] bf16. kshift = log2(K). Tiny matrices, L2-resident.
__global__ __launch_bounds__(256) void conv_wt(const float* __restrict__ W,
                                               short* __restrict__ Wt,
                                               int kshift, int N)
{
    const int o = blockIdx.x * 256 + threadIdx.x;   // output index n*K+k
    const int K = 1 << kshift;
    const int n = o >> kshift;
    const int k = o & (K - 1);
    Wt[o] = f2bf(W[(long)k * N + n]);
}

// ---------------------------------------------------------------------------
// bf16 MFMA GEMM, both operands pre-converted: C[M,N] = A[M,K] * Bt[N,K]^T.
// 128x128 tile, BK=32, 4 waves 2x2 of 64x64, 16x16x32 MFMA (layouts per
// m89/m91; ran correct in rounds 4-7). LDS rows padded to 40 shorts (80 B).
// Staging: 2 threads/row, each writes 16 shorts (two short8s) = full tile.
// OUTBF16: C bf16; else f32 + optional bias.
// ---------------------------------------------------------------------------
template<int OUTBF16>
__global__ __launch_bounds__(256) void gemm_tt(const short* __restrict__ A,
                                               const short* __restrict__ Bt,
                                               const float* __restrict__ bias,
                                               void* __restrict__ C_,
                                               int N, int Kd)
{
    __shared__ short As[128][40];
    __shared__ short Bs[128][40];

    const int tid  = threadIdx.x;
    const int lane = tid & 63;
    const int wv   = tid >> 6;
    const int quad = lane >> 4;
    const int l15  = lane & 15;
    const int m0 = blockIdx.y * 128;
    const int n0 = blockIdx.x * 128;
    const int mh = (wv & 1) * 64, nh = (wv >> 1) * 64;

    const int srow  = tid >> 1;          // 0..127
    const int shalf = (tid & 1) * 16;    // 0 or 16

    float4v acc[4][4];
#pragma unroll
    for (int i = 0; i < 4; ++i)
#pragma unroll
        for (int j = 0; j < 4; ++j) acc[i][j] = (float4v)(0.f);

    for (int k0 = 0; k0 < Kd; k0 += 32) {
        const short8* asrc = (const short8*)(A + (long)(m0 + srow) * Kd + k0 + shalf);
        const short8* bsrc = (const short8*)(Bt + (long)(n0 + srow) * Kd + k0 + shalf);
        *(short8*)&As[srow][shalf]     = asrc[0];
        *(short8*)&As[srow][shalf + 8] = asrc[1];
        *(short8*)&Bs[srow][shalf]     = bsrc[0];
        *(short8*)&Bs[srow][shalf + 8] = bsrc[1];
        __syncthreads();

        short8 af[4], bfv[4];
#pragma unroll
        for (int i = 0; i < 4; ++i)
            af[i] = *(const short8*)&As[mh + i * 16 + l15][quad * 8];
#pragma unroll
        for (int j = 0; j < 4; ++j)
            bfv[j] = *(const short8*)&Bs[nh + j * 16 + l15][quad * 8];
#pragma unroll
        for (int i = 0; i < 4; ++i)
#pragma unroll
            for (int j = 0; j < 4; ++j)
                acc[i][j] = __builtin_amdgcn_mfma_f32_16x16x32_bf16(af[i], bfv[j], acc[i][j], 0, 0, 0);
        __syncthreads();
    }

#pragma unroll
    for (int i = 0; i < 4; ++i)
#pragma unroll
        for (int j = 0; j < 4; ++j) {
            const int col = n0 + nh + j * 16 + l15;
            const float bb = (!OUTBF16 && bias) ? bias[col] : 0.f;
#pragma unroll
            for (int r = 0; r < 4; ++r) {
                const int row = m0 + mh + i * 16 + quad * 4 + r;
                if (OUTBF16) {
                    ((short*)C_)[(long)row * N + col] = f2bf(acc[i][j][r]);
                } else {
                    ((float*)C_)[(long)row * N + col] = acc[i][j][r] + bb;
                }
            }
        }
}

// ---------------------------------------------------------------------------
// Fused KNN attention, bf16 storage / f32 math (unchanged from round 5).
// ---------------------------------------------------------------------------
__global__ __launch_bounds__(256) void attn_kernel(const short* qall,
                                                   const short* __restrict__ kvall,
                                                   const int* __restrict__ idxp,
                                                   short* outp)
{
    __shared__ float attn_s[4][8][8];
    const int wave = threadIdx.x >> 6;
    const int lane = threadIdx.x & 63;
    const int g = blockIdx.x * 4 + wave;
    const int b = g >> 13;
    const int* myidx = idxp + (long)g * 8;

    {
        const int h = lane >> 3;
        const int k = lane & 7;
        const int j = myidx[k];
        const short8* qrow = (const short8*)(qall + (long)g * 512 + h * 64);
        const short8* krow = (const short8*)(kvall + ((long)(b * N_PTS + j)) * 1024 + h * 64);

        float dot = 0.f;
#pragma unroll
        for (int c = 0; c < 8; ++c) {
            const short8 qv = qrow[c];
            const short8 kv = krow[c];
#pragma unroll
            for (int e = 0; e < 8; ++e)
                dot = fmaf(bf2f(qv[e]), bf2f(kv[e]), dot);
        }
        dot *= 0.125f;

        float m = dot;
#pragma unroll
        for (int off = 1; off < 8; off <<= 1)
            m = fmaxf(m, __shfl_xor(m, off, 8));
        const float e = __expf(dot - m);
        float ssum = e;
#pragma unroll
        for (int off = 1; off < 8; off <<= 1)
            ssum += __shfl_xor(ssum, off, 8);
        attn_s[wave][h][k] = e / ssum;
    }
    __syncthreads();                      // drains q reads before aliased writes

    const int d8 = lane * 8;
    const int h2 = lane >> 3;
    float o[8] = {0.f, 0.f, 0.f, 0.f, 0.f, 0.f, 0.f, 0.f};
#pragma unroll
    for (int kk = 0; kk < 8; ++kk) {
        const int jj = myidx[kk];
        const float w = attn_s[wave][h2][kk];
        const short8 v = *(const short8*)(kvall + ((long)(b * N_PTS + jj)) * 1024 + 512 + d8);
#pragma unroll
        for (int e = 0; e < 8; ++e)
            o[e] = fmaf(w, bf2f(v[e]), o[e]);
    }
    short8 ov = {f2bf(o[0]), f2bf(o[1]), f2bf(o[2]), f2bf(o[3]),
                 f2bf(o[4]), f2bf(o[5]), f2bf(o[6]), f2bf(o[7])};
    *(short8*)(outp + (long)g * 512 + d8) = ov;
}

// ---------------------------------------------------------------------------
extern "C" void kernel_launch(void* const* d_in, const int* in_sizes, int n_in,
                              void* d_out, int out_size, void* d_ws, size_t ws_size,
                              hipStream_t stream)
{
    const float* x    = (const float*)d_in[0];  // [2,8192,256]
    const float* pos  = (const float*)d_in[1];  // [2,8192,3]
    const float* Wq   = (const float*)d_in[2];  // [256,512]
    const float* Wkv  = (const float*)d_in[3];  // [256,1024]
    const float* Wout = (const float*)d_in[4];  // [512,256]
    const float* bout = (const float*)d_in[5];  // [256]
    float* out = (float*)d_out;                 // [2,8192,256] f32

    const int M = 16384;

    // workspace layout:
    char* ws = (char*)d_ws;
    int*   idxp  = (int*)ws;                          ws += 1 << 19;  // 512 KB
    short* qall  = (short*)ws;                        ws += (long)M * 512 * 2;   // 16 MB
    short* kvall = (short*)ws;                        ws += (long)M * 1024 * 2;  // 32 MB
    short* xb    = (short*)ws;                        ws += (long)M * 256 * 2;   // 8 MB
    short* wqt   = (short*)ws;                        ws += 512 * 256 * 2;
    short* wkvt  = (short*)ws;                        ws += 1024 * 256 * 2;
    short* woutt = (short*)ws;                        ws += 256 * 512 * 2;
    // knn scratch (16.8 MB) aliases kvall; consumed by merge before kv-gemm
    u64* partial = (u64*)kvall;

    knn_partial<<<1024, 256, 0, stream>>>(pos, partial);
    knn_merge<<<64, 256, 0, stream>>>(partial, idxp);

    conv_x<<<2048, 256, 0, stream>>>(x, xb);
    conv_wt<<<512, 256, 0, stream>>>(Wq, wqt, 8, 512);       // [256,512] -> [512,256]
    conv_wt<<<1024, 256, 0, stream>>>(Wkv, wkvt, 8, 1024);   // [256,1024] -> [1024,256]
    conv_wt<<<512, 256, 0, stream>>>(Wout, woutt, 9, 256);   // [512,256] -> [256,512]

    gemm_tt<1><<<dim3(4, 128), 256, 0, stream>>>(xb, wqt, nullptr, qall, 512, 256);
    gemm_tt<1><<<dim3(8, 128), 256, 0, stream>>>(xb, wkvt, nullptr, kvall, 1024, 256);
    attn_kernel<<<M / 4, 256, 0, stream>>>(qall, kvall, idxp, qall);   // in-place
    gemm_tt<0><<<dim3(2, 128), 256, 0, stream>>>(qall, woutt, bout, out, 256, 512);
}